// Round 1
// baseline (1349.053 us; speedup 1.0000x reference)
//
#include <hip/hip_runtime.h>
#include <hip/hip_bf16.h>
#include <math.h>

#define D_DIM 1024
#define F_DIM 4096
#define N_EXP 8
#define PK 40   // padded LDS leading dim (bf16 elems); multiple of 8 keeps 16B-aligned frag reads, breaks pow2 conflicts

typedef __attribute__((ext_vector_type(4))) float f32x4;
typedef __attribute__((ext_vector_type(8))) short bf16x8;

__device__ __forceinline__ unsigned short f2bf(float f) {
    union { float f; unsigned int u; } v; v.f = f;
    unsigned int r = v.u + 0x7fffu + ((v.u >> 16) & 1u);  // RNE
    return (unsigned short)(r >> 16);
}

// ---------------- cast x fp32 -> bf16 ----------------
__global__ void cast_x_kernel(const float* __restrict__ x, unsigned short* __restrict__ xb, int n4) {
    int i = blockIdx.x * blockDim.x + threadIdx.x;
    if (i >= n4) return;
    float4 v = ((const float4*)x)[i];
    unsigned int lo = (unsigned int)f2bf(v.x) | ((unsigned int)f2bf(v.y) << 16);
    unsigned int hi = (unsigned int)f2bf(v.z) | ((unsigned int)f2bf(v.w) << 16);
    ((uint2*)xb)[i] = make_uint2(lo, hi);
}

// ---------------- gating: softmax top-2 + compaction ----------------
__global__ void gate_kernel(const float* __restrict__ x, const float* __restrict__ gw,
                            int* __restrict__ counts, int* __restrict__ perm,
                            float* __restrict__ wts, int T) {
    int wid = threadIdx.x >> 6, lane = threadIdx.x & 63;
    int token = blockIdx.x * 4 + wid;
    if (token >= T) return;
    float acc[N_EXP];
#pragma unroll
    for (int e = 0; e < N_EXP; e++) acc[e] = 0.f;
    const float* xr = x + (size_t)token * D_DIM;
    for (int i = 0; i < D_DIM / 64; i++) {
        int d = lane + 64 * i;
        float v = xr[d];
#pragma unroll
        for (int e = 0; e < N_EXP; e++) acc[e] += v * gw[d * N_EXP + e];
    }
#pragma unroll
    for (int off = 32; off >= 1; off >>= 1) {
#pragma unroll
        for (int e = 0; e < N_EXP; e++) acc[e] += __shfl_xor(acc[e], off, 64);
    }
    if (lane == 0) {
        float m = acc[0];
#pragma unroll
        for (int e = 1; e < N_EXP; e++) m = fmaxf(m, acc[e]);
        float p[N_EXP];
#pragma unroll
        for (int e = 0; e < N_EXP; e++) p[e] = expf(acc[e] - m);
        int a = 0;
        for (int e = 1; e < N_EXP; e++) if (p[e] > p[a]) a = e;
        int b = (a == 0) ? 1 : 0;
        for (int e = 0; e < N_EXP; e++) if (e != a && p[e] > p[b]) b = e;
        float s = p[a] + p[b];
        int pa = atomicAdd(&counts[a], 1);
        perm[(size_t)a * T + pa] = token; wts[(size_t)a * T + pa] = p[a] / s;
        int pb = atomicAdd(&counts[b], 1);
        perm[(size_t)b * T + pb] = token; wts[(size_t)b * T + pb] = p[b] / s;
    }
}

__global__ void offsets_kernel(const int* __restrict__ counts, int* __restrict__ offs) {
    if (threadIdx.x == 0 && blockIdx.x == 0) {
        int s = 0;
        for (int e = 0; e < N_EXP; e++) { offs[e] = s; s += counts[e]; }
        offs[N_EXP] = s;
    }
}

// ---------------- GEMM1: H = silu(Xe@W1e) * (Xe@W3e), bf16 out ----------------
__global__ __launch_bounds__(256, 2) void gemm1_kernel(
    const unsigned short* __restrict__ xb, const float* __restrict__ w1,
    const float* __restrict__ w3, const int* __restrict__ counts,
    const int* __restrict__ offs, const int* __restrict__ perm,
    unsigned short* __restrict__ hbuf, int T)
{
    int e = blockIdx.z, rt = blockIdx.x, ct = blockIdx.y;
    int n_e = counts[e];
    int row0 = rt * 128;
    if (row0 >= n_e) return;
    int c0 = ct * 128;
    const float* w1e = w1 + (size_t)e * D_DIM * F_DIM;
    const float* w3e = w3 + (size_t)e * D_DIM * F_DIM;
    __shared__ unsigned short As[128 * PK];
    __shared__ unsigned short B1s[128 * PK];
    __shared__ unsigned short B3s[128 * PK];
    int tid = threadIdx.x;
    int wid = tid >> 6, lane = tid & 63;
    int wm = wid >> 1, wn = wid & 1;
    int q = lane >> 4, ln = lane & 15;

    // A staging: thread pair per row, 32B each half
    int ar = tid >> 1, ah = tid & 1;
    int tok = perm[(size_t)e * T + min(row0 + ar, n_e - 1)];
    const unsigned short* aptr = xb + (size_t)tok * D_DIM + ah * 16;
    // B staging: thread -> (k row, 16-col chunk)
    int bk = tid >> 3;            // 0..31
    int bn = (tid & 7) * 16;      // 0..112

    f32x4 acc1[4][4], acc3[4][4];
#pragma unroll
    for (int i = 0; i < 4; i++)
#pragma unroll
        for (int j = 0; j < 4; j++) {
            acc1[i][j] = (f32x4){0.f, 0.f, 0.f, 0.f};
            acc3[i][j] = (f32x4){0.f, 0.f, 0.f, 0.f};
        }

    for (int k0 = 0; k0 < D_DIM; k0 += 32) {
        bf16x8 a0 = *(const bf16x8*)(aptr + k0);
        bf16x8 a1 = *(const bf16x8*)(aptr + k0 + 8);
        *(bf16x8*)&As[ar * PK + ah * 16] = a0;
        *(bf16x8*)&As[ar * PK + ah * 16 + 8] = a1;
        const float* b1p = w1e + (size_t)(k0 + bk) * F_DIM + c0 + bn;
        const float* b3p = w3e + (size_t)(k0 + bk) * F_DIM + c0 + bn;
#pragma unroll
        for (int j = 0; j < 4; j++) {
            float4 f = ((const float4*)b1p)[j];
            B1s[(bn + 4 * j + 0) * PK + bk] = f2bf(f.x);
            B1s[(bn + 4 * j + 1) * PK + bk] = f2bf(f.y);
            B1s[(bn + 4 * j + 2) * PK + bk] = f2bf(f.z);
            B1s[(bn + 4 * j + 3) * PK + bk] = f2bf(f.w);
        }
#pragma unroll
        for (int j = 0; j < 4; j++) {
            float4 f = ((const float4*)b3p)[j];
            B3s[(bn + 4 * j + 0) * PK + bk] = f2bf(f.x);
            B3s[(bn + 4 * j + 1) * PK + bk] = f2bf(f.y);
            B3s[(bn + 4 * j + 2) * PK + bk] = f2bf(f.z);
            B3s[(bn + 4 * j + 3) * PK + bk] = f2bf(f.w);
        }
        __syncthreads();
        bf16x8 af[4];
#pragma unroll
        for (int i = 0; i < 4; i++)
            af[i] = *(const bf16x8*)&As[(wm * 64 + i * 16 + ln) * PK + q * 8];
#pragma unroll
        for (int j = 0; j < 4; j++) {
            bf16x8 bfr = *(const bf16x8*)&B1s[(wn * 64 + j * 16 + ln) * PK + q * 8];
#pragma unroll
            for (int i = 0; i < 4; i++)
                acc1[i][j] = __builtin_amdgcn_mfma_f32_16x16x32_bf16(af[i], bfr, acc1[i][j], 0, 0, 0);
        }
#pragma unroll
        for (int j = 0; j < 4; j++) {
            bf16x8 bfr = *(const bf16x8*)&B3s[(wn * 64 + j * 16 + ln) * PK + q * 8];
#pragma unroll
            for (int i = 0; i < 4; i++)
                acc3[i][j] = __builtin_amdgcn_mfma_f32_16x16x32_bf16(af[i], bfr, acc3[i][j], 0, 0, 0);
        }
        __syncthreads();
    }
    // epilogue: SwiGLU, store bf16 H (packed rows: offs[e]+grow)
    int hb = offs[e];
#pragma unroll
    for (int i = 0; i < 4; i++) {
#pragma unroll
        for (int r = 0; r < 4; r++) {
            int rl = wm * 64 + i * 16 + q * 4 + r;
            int grow = row0 + rl;
            if (grow < n_e) {
                size_t hrow = (size_t)(hb + grow) * F_DIM;
#pragma unroll
                for (int j = 0; j < 4; j++) {
                    int col = c0 + wn * 64 + j * 16 + ln;
                    float p1 = acc1[i][j][r];
                    float p3 = acc3[i][j][r];
                    float h = (p1 / (1.f + expf(-p1))) * p3;
                    hbuf[hrow + col] = f2bf(h);
                }
            }
        }
    }
}

// ---------------- GEMM2: out[token] += (He @ W2e) * w ----------------
__global__ __launch_bounds__(256, 2) void gemm2_kernel(
    const unsigned short* __restrict__ hbuf, const float* __restrict__ w2,
    const int* __restrict__ counts, const int* __restrict__ offs,
    const int* __restrict__ perm, const float* __restrict__ wts,
    float* __restrict__ out, int T)
{
    int e = blockIdx.z, rt = blockIdx.x, ct = blockIdx.y;
    int n_e = counts[e];
    int row0 = rt * 128;
    if (row0 >= n_e) return;
    int c0 = ct * 128;
    const float* w2e = w2 + (size_t)e * F_DIM * D_DIM;
    __shared__ unsigned short As[128 * PK];
    __shared__ unsigned short Bs[128 * PK];
    int tid = threadIdx.x;
    int wid = tid >> 6, lane = tid & 63;
    int wm = wid >> 1, wn = wid & 1;
    int q = lane >> 4, ln = lane & 15;

    int hb = offs[e];
    int ar = tid >> 1, ah = tid & 1;
    int hrow_s = hb + min(row0 + ar, n_e - 1);
    const unsigned short* aptr = hbuf + (size_t)hrow_s * F_DIM + ah * 16;
    int bk = tid >> 3;
    int bn = (tid & 7) * 16;

    f32x4 acc[4][4];
#pragma unroll
    for (int i = 0; i < 4; i++)
#pragma unroll
        for (int j = 0; j < 4; j++) acc[i][j] = (f32x4){0.f, 0.f, 0.f, 0.f};

    for (int k0 = 0; k0 < F_DIM; k0 += 32) {
        bf16x8 a0 = *(const bf16x8*)(aptr + k0);
        bf16x8 a1 = *(const bf16x8*)(aptr + k0 + 8);
        *(bf16x8*)&As[ar * PK + ah * 16] = a0;
        *(bf16x8*)&As[ar * PK + ah * 16 + 8] = a1;
        const float* bp = w2e + (size_t)(k0 + bk) * D_DIM + c0 + bn;
#pragma unroll
        for (int j = 0; j < 4; j++) {
            float4 f = ((const float4*)bp)[j];
            Bs[(bn + 4 * j + 0) * PK + bk] = f2bf(f.x);
            Bs[(bn + 4 * j + 1) * PK + bk] = f2bf(f.y);
            Bs[(bn + 4 * j + 2) * PK + bk] = f2bf(f.z);
            Bs[(bn + 4 * j + 3) * PK + bk] = f2bf(f.w);
        }
        __syncthreads();
        bf16x8 af[4];
#pragma unroll
        for (int i = 0; i < 4; i++)
            af[i] = *(const bf16x8*)&As[(wm * 64 + i * 16 + ln) * PK + q * 8];
#pragma unroll
        for (int j = 0; j < 4; j++) {
            bf16x8 bfr = *(const bf16x8*)&Bs[(wn * 64 + j * 16 + ln) * PK + q * 8];
#pragma unroll
            for (int i = 0; i < 4; i++)
                acc[i][j] = __builtin_amdgcn_mfma_f32_16x16x32_bf16(af[i], bfr, acc[i][j], 0, 0, 0);
        }
        __syncthreads();
    }
#pragma unroll
    for (int i = 0; i < 4; i++) {
#pragma unroll
        for (int r = 0; r < 4; r++) {
            int rl = wm * 64 + i * 16 + q * 4 + r;
            int grow = row0 + rl;
            if (grow < n_e) {
                int token = perm[(size_t)e * T + grow];
                float w = wts[(size_t)e * T + grow];
                float* orow = out + (size_t)token * D_DIM + c0;
#pragma unroll
                for (int j = 0; j < 4; j++) {
                    int col = wn * 64 + j * 16 + ln;
                    atomicAdd(&orow[col], acc[i][j][r] * w);
                }
            }
        }
    }
}

extern "C" void kernel_launch(void* const* d_in, const int* in_sizes, int n_in,
                              void* d_out, int out_size, void* d_ws, size_t ws_size,
                              hipStream_t stream) {
    const float* x  = (const float*)d_in[0];
    const float* gw = (const float*)d_in[1];
    const float* w1 = (const float*)d_in[2];
    const float* w2 = (const float*)d_in[3];
    const float* w3 = (const float*)d_in[4];
    float* out = (float*)d_out;
    int T = in_sizes[0] / D_DIM;   // 2048

    char* ws = (char*)d_ws;
    unsigned short* xb = (unsigned short*)ws;
    size_t off = (size_t)T * D_DIM * 2;
    int* counts = (int*)(ws + off); off += 256;
    int* offs   = (int*)(ws + off); off += 256;
    int* perm   = (int*)(ws + off); off += (size_t)N_EXP * T * 4;
    float* wts  = (float*)(ws + off); off += (size_t)N_EXP * T * 4;
    unsigned short* hbuf = (unsigned short*)(ws + off);  // [2T, F] bf16 packed

    hipMemsetAsync(counts, 0, 256, stream);
    hipMemsetAsync(out, 0, (size_t)out_size * sizeof(float), stream);

    int n4 = T * D_DIM / 4;
    cast_x_kernel<<<(n4 + 255) / 256, 256, 0, stream>>>(x, xb, n4);
    gate_kernel<<<T / 4, 256, 0, stream>>>(x, gw, counts, perm, wts, T);
    offsets_kernel<<<1, 64, 0, stream>>>(counts, offs);

    dim3 g1(T / 128, F_DIM / 128, N_EXP);
    gemm1_kernel<<<g1, 256, 0, stream>>>(xb, w1, w3, counts, offs, perm, hbuf, T);
    dim3 g2(T / 128, D_DIM / 128, N_EXP);
    gemm2_kernel<<<g2, 256, 0, stream>>>(hbuf, w2, counts, offs, perm, wts, out, T);
}

// Round 2
// 1093.724 us; speedup vs baseline: 1.2334x; 1.2334x over previous
//
#include <hip/hip_runtime.h>
#include <hip/hip_bf16.h>
#include <math.h>

#define D_DIM 1024
#define F_DIM 4096
#define N_EXP 8

typedef __attribute__((ext_vector_type(4))) float f32x4;
typedef __attribute__((ext_vector_type(8))) short bf16x8;

__device__ __forceinline__ unsigned short f2bf(float f) {
    union { float f; unsigned int u; } v; v.f = f;
    unsigned int r = v.u + 0x7fffu + ((v.u >> 16) & 1u);  // RNE
    return (unsigned short)(r >> 16);
}

// async global->LDS, 16B per lane; LDS dest = lds_ptr(wave-uniform) + lane*16
#define GLDS16(g, l) __builtin_amdgcn_global_load_lds( \
    (const __attribute__((address_space(1))) void*)(g), \
    (__attribute__((address_space(3))) void*)(l), 16, 0, 0)

// ---------------- cast x fp32 -> bf16 ----------------
__global__ void cast_x_kernel(const float* __restrict__ x, unsigned short* __restrict__ xb, int n4) {
    int i = blockIdx.x * blockDim.x + threadIdx.x;
    if (i >= n4) return;
    float4 v = ((const float4*)x)[i];
    unsigned int lo = (unsigned int)f2bf(v.x) | ((unsigned int)f2bf(v.y) << 16);
    unsigned int hi = (unsigned int)f2bf(v.z) | ((unsigned int)f2bf(v.w) << 16);
    ((uint2*)xb)[i] = make_uint2(lo, hi);
}

// ---------------- transpose + cast: in [R][C] fp32 -> out [C][R] bf16 ----------------
// grid: (C/64, R/64, E); block 256
__global__ __launch_bounds__(256) void transpose_cast_kernel(
    const float* __restrict__ in, unsigned short* __restrict__ out, int R, int C) {
    __shared__ float tile[64][65];
    const float* inp = in + (size_t)blockIdx.z * R * C;
    unsigned short* outp = out + (size_t)blockIdx.z * R * C;
    int r0 = blockIdx.y * 64, c0 = blockIdx.x * 64;
    int tid = threadIdx.x;
    int tr = tid >> 4, tc = (tid & 15) * 4;
#pragma unroll
    for (int i = 0; i < 4; i++) {
        float4 v = *(const float4*)(inp + (size_t)(r0 + tr + i * 16) * C + c0 + tc);
        tile[tr + i * 16][tc + 0] = v.x;
        tile[tr + i * 16][tc + 1] = v.y;
        tile[tr + i * 16][tc + 2] = v.z;
        tile[tr + i * 16][tc + 3] = v.w;
    }
    __syncthreads();
    int wc = tid >> 4, wr = (tid & 15) * 4;
#pragma unroll
    for (int i = 0; i < 4; i++) {
        int c = wc + i * 16;
        ushort4 o;
        o.x = f2bf(tile[wr + 0][c]);
        o.y = f2bf(tile[wr + 1][c]);
        o.z = f2bf(tile[wr + 2][c]);
        o.w = f2bf(tile[wr + 3][c]);
        *(ushort4*)(outp + (size_t)(c0 + c) * R + r0 + wr) = o;
    }
}

// ---------------- gating: softmax top-2 + compaction ----------------
__global__ void gate_kernel(const float* __restrict__ x, const float* __restrict__ gw,
                            int* __restrict__ counts, int* __restrict__ perm,
                            float* __restrict__ wts, int T) {
    int wid = threadIdx.x >> 6, lane = threadIdx.x & 63;
    int token = blockIdx.x * 4 + wid;
    if (token >= T) return;
    float acc[N_EXP];
#pragma unroll
    for (int e = 0; e < N_EXP; e++) acc[e] = 0.f;
    const float* xr = x + (size_t)token * D_DIM;
    for (int i = 0; i < D_DIM / 64; i++) {
        int d = lane + 64 * i;
        float v = xr[d];
#pragma unroll
        for (int e = 0; e < N_EXP; e++) acc[e] += v * gw[d * N_EXP + e];
    }
#pragma unroll
    for (int off = 32; off >= 1; off >>= 1) {
#pragma unroll
        for (int e = 0; e < N_EXP; e++) acc[e] += __shfl_xor(acc[e], off, 64);
    }
    if (lane == 0) {
        float m = acc[0];
#pragma unroll
        for (int e = 1; e < N_EXP; e++) m = fmaxf(m, acc[e]);
        float p[N_EXP];
#pragma unroll
        for (int e = 0; e < N_EXP; e++) p[e] = expf(acc[e] - m);
        int a = 0;
        for (int e = 1; e < N_EXP; e++) if (p[e] > p[a]) a = e;
        int b = (a == 0) ? 1 : 0;
        for (int e = 0; e < N_EXP; e++) if (e != a && p[e] > p[b]) b = e;
        float s = p[a] + p[b];
        int pa = atomicAdd(&counts[a], 1);
        perm[(size_t)a * T + pa] = token; wts[(size_t)a * T + pa] = p[a] / s;
        int pb = atomicAdd(&counts[b], 1);
        perm[(size_t)b * T + pb] = token; wts[(size_t)b * T + pb] = p[b] / s;
    }
}

__global__ void offsets_kernel(const int* __restrict__ counts, int* __restrict__ offs) {
    if (threadIdx.x == 0 && blockIdx.x == 0) {
        int s = 0;
        for (int e = 0; e < N_EXP; e++) { offs[e] = s; s += counts[e]; }
        offs[N_EXP] = s;
    }
}

// ---------------- GEMM1: H = silu(Xe@W1e^T') * (Xe@W3e^T'), 128x64 tile ----------------
// w1t/w3t: [E][F][D] bf16 (k-contiguous per output col). LDS rows: 32 bf16 = 64B,
// chunk swizzle: slot c holds global chunk c ^ ((row>>1)&3)  -> 2-way banks (free).
__global__ __launch_bounds__(256) void gemm1_kernel(
    const unsigned short* __restrict__ xb, const unsigned short* __restrict__ w1t,
    const unsigned short* __restrict__ w3t, const int* __restrict__ counts,
    const int* __restrict__ offs, const int* __restrict__ perm,
    unsigned short* __restrict__ hbuf, int T)
{
    int e = blockIdx.z, rt = blockIdx.x, ct = blockIdx.y;
    int n_e = counts[e];
    int row0 = rt * 128;
    if (row0 >= n_e) return;
    int c0 = ct * 64;
    const unsigned short* w1e = w1t + (size_t)e * F_DIM * D_DIM;
    const unsigned short* w3e = w3t + (size_t)e * F_DIM * D_DIM;
    __shared__ unsigned short As[128 * 32];
    __shared__ unsigned short B1s[64 * 32];
    __shared__ unsigned short B3s[64 * 32];
    int tid = threadIdx.x;
    int wid = tid >> 6, lane = tid & 63;
    int wm = wid >> 1, wn = wid & 1;
    int q = lane >> 4, ln = lane & 15;

    // staging: thread -> row sr = tid>>2, chunk sc = tid&3; swizzled global chunk
    int sr = tid >> 2, sc = tid & 3;
    int q0 = sc ^ ((sr >> 1) & 3);           // same for sr and sr+64
    int tok0 = perm[(size_t)e * T + min(row0 + sr, n_e - 1)];
    int tok1 = perm[(size_t)e * T + min(row0 + sr + 64, n_e - 1)];
    const unsigned short* ag0 = xb + (size_t)tok0 * D_DIM + q0 * 8;
    const unsigned short* ag1 = xb + (size_t)tok1 * D_DIM + q0 * 8;
    const unsigned short* b1g = w1e + (size_t)(c0 + sr) * D_DIM + q0 * 8;
    const unsigned short* b3g = w3e + (size_t)(c0 + sr) * D_DIM + q0 * 8;
    unsigned short* as_w = &As[wid * 512];        // wave-uniform LDS bases (bytes: wid*1024)
    unsigned short* b1_w = &B1s[wid * 512];
    unsigned short* b3_w = &B3s[wid * 512];

    // frag-read offsets (u16 elems), loop-invariant, swizzle folded in
    int a_off[4], b_off[2];
#pragma unroll
    for (int i = 0; i < 4; i++) {
        int m = wm * 64 + i * 16 + ln;
        a_off[i] = m * 32 + (q ^ ((m >> 1) & 3)) * 8;
    }
#pragma unroll
    for (int j = 0; j < 2; j++) {
        int n = wn * 32 + j * 16 + ln;
        b_off[j] = n * 32 + (q ^ ((n >> 1) & 3)) * 8;
    }

    f32x4 acc1[4][2], acc3[4][2];
#pragma unroll
    for (int i = 0; i < 4; i++)
#pragma unroll
        for (int j = 0; j < 2; j++) {
            acc1[i][j] = (f32x4){0.f, 0.f, 0.f, 0.f};
            acc3[i][j] = (f32x4){0.f, 0.f, 0.f, 0.f};
        }

    for (int k0 = 0; k0 < D_DIM; k0 += 32) {
        GLDS16(ag0 + k0, as_w);
        GLDS16(ag1 + k0, as_w + 2048);
        GLDS16(b1g + k0, b1_w);
        GLDS16(b3g + k0, b3_w);
        __syncthreads();
        bf16x8 af[4];
#pragma unroll
        for (int i = 0; i < 4; i++) af[i] = *(const bf16x8*)&As[a_off[i]];
#pragma unroll
        for (int j = 0; j < 2; j++) {
            bf16x8 b1f = *(const bf16x8*)&B1s[b_off[j]];
            bf16x8 b3f = *(const bf16x8*)&B3s[b_off[j]];
#pragma unroll
            for (int i = 0; i < 4; i++) {
                acc1[i][j] = __builtin_amdgcn_mfma_f32_16x16x32_bf16(af[i], b1f, acc1[i][j], 0, 0, 0);
                acc3[i][j] = __builtin_amdgcn_mfma_f32_16x16x32_bf16(af[i], b3f, acc3[i][j], 0, 0, 0);
            }
        }
        __syncthreads();
    }
    int hb = offs[e];
#pragma unroll
    for (int i = 0; i < 4; i++) {
#pragma unroll
        for (int r = 0; r < 4; r++) {
            int grow = row0 + wm * 64 + i * 16 + q * 4 + r;
            if (grow < n_e) {
                size_t hrow = (size_t)(hb + grow) * F_DIM;
#pragma unroll
                for (int j = 0; j < 2; j++) {
                    int col = c0 + wn * 32 + j * 16 + ln;
                    float p1 = acc1[i][j][r];
                    float p3 = acc3[i][j][r];
                    float h = (p1 / (1.f + expf(-p1))) * p3;
                    hbuf[hrow + col] = f2bf(h);
                }
            }
        }
    }
}

// ---------------- GEMM2: out[token] += (He @ W2e) * w, 128x64 tile ----------------
__global__ __launch_bounds__(256) void gemm2_kernel(
    const unsigned short* __restrict__ hbuf, const unsigned short* __restrict__ w2t,
    const int* __restrict__ counts, const int* __restrict__ offs,
    const int* __restrict__ perm, const float* __restrict__ wts,
    float* __restrict__ out, int T)
{
    int e = blockIdx.z, rt = blockIdx.x, ct = blockIdx.y;
    int n_e = counts[e];
    int row0 = rt * 128;
    if (row0 >= n_e) return;
    int c0 = ct * 64;
    const unsigned short* w2e = w2t + (size_t)e * D_DIM * F_DIM;  // [D][F] bf16
    __shared__ unsigned short As[128 * 32];
    __shared__ unsigned short Bs[64 * 32];
    int tid = threadIdx.x;
    int wid = tid >> 6, lane = tid & 63;
    int wm = wid >> 1, wn = wid & 1;
    int q = lane >> 4, ln = lane & 15;
    int hb = offs[e];

    int sr = tid >> 2, sc = tid & 3;
    int q0 = sc ^ ((sr >> 1) & 3);
    int ar0 = hb + min(row0 + sr, n_e - 1);
    int ar1 = hb + min(row0 + sr + 64, n_e - 1);
    const unsigned short* ag0 = hbuf + (size_t)ar0 * F_DIM + q0 * 8;
    const unsigned short* ag1 = hbuf + (size_t)ar1 * F_DIM + q0 * 8;
    const unsigned short* bg  = w2e + (size_t)(c0 + sr) * F_DIM + q0 * 8;
    unsigned short* as_w = &As[wid * 512];
    unsigned short* b_w  = &Bs[wid * 512];

    int a_off[4], b_off[2];
#pragma unroll
    for (int i = 0; i < 4; i++) {
        int m = wm * 64 + i * 16 + ln;
        a_off[i] = m * 32 + (q ^ ((m >> 1) & 3)) * 8;
    }
#pragma unroll
    for (int j = 0; j < 2; j++) {
        int n = wn * 32 + j * 16 + ln;
        b_off[j] = n * 32 + (q ^ ((n >> 1) & 3)) * 8;
    }

    f32x4 acc[4][2];
#pragma unroll
    for (int i = 0; i < 4; i++)
#pragma unroll
        for (int j = 0; j < 2; j++) acc[i][j] = (f32x4){0.f, 0.f, 0.f, 0.f};

    for (int k0 = 0; k0 < F_DIM; k0 += 32) {
        GLDS16(ag0 + k0, as_w);
        GLDS16(ag1 + k0, as_w + 2048);
        GLDS16(bg + k0, b_w);
        __syncthreads();
        bf16x8 af[4];
#pragma unroll
        for (int i = 0; i < 4; i++) af[i] = *(const bf16x8*)&As[a_off[i]];
#pragma unroll
        for (int j = 0; j < 2; j++) {
            bf16x8 bf = *(const bf16x8*)&Bs[b_off[j]];
#pragma unroll
            for (int i = 0; i < 4; i++)
                acc[i][j] = __builtin_amdgcn_mfma_f32_16x16x32_bf16(af[i], bf, acc[i][j], 0, 0, 0);
        }
        __syncthreads();
    }
#pragma unroll
    for (int i = 0; i < 4; i++) {
#pragma unroll
        for (int r = 0; r < 4; r++) {
            int grow = row0 + wm * 64 + i * 16 + q * 4 + r;
            if (grow < n_e) {
                int token = perm[(size_t)e * T + grow];
                float w = wts[(size_t)e * T + grow];
                float* orow = out + (size_t)token * D_DIM;
#pragma unroll
                for (int j = 0; j < 2; j++) {
                    int col = c0 + wn * 32 + j * 16 + ln;
                    atomicAdd(&orow[col], acc[i][j][r] * w);
                }
            }
        }
    }
}

extern "C" void kernel_launch(void* const* d_in, const int* in_sizes, int n_in,
                              void* d_out, int out_size, void* d_ws, size_t ws_size,
                              hipStream_t stream) {
    const float* x  = (const float*)d_in[0];
    const float* gw = (const float*)d_in[1];
    const float* w1 = (const float*)d_in[2];
    const float* w2 = (const float*)d_in[3];
    const float* w3 = (const float*)d_in[4];
    float* out = (float*)d_out;
    int T = in_sizes[0] / D_DIM;   // 2048

    char* ws = (char*)d_ws;
    size_t off = 0;
    unsigned short* xb = (unsigned short*)(ws + off); off += (size_t)T * D_DIM * 2;
    int* counts = (int*)(ws + off); off += 256;
    int* offs   = (int*)(ws + off); off += 256;
    int* perm   = (int*)(ws + off); off += (size_t)N_EXP * T * 4;
    float* wts  = (float*)(ws + off); off += (size_t)N_EXP * T * 4;
    unsigned short* hbuf = (unsigned short*)(ws + off); off += (size_t)2 * T * F_DIM * 2;
    unsigned short* w1t  = (unsigned short*)(ws + off); off += (size_t)N_EXP * D_DIM * F_DIM * 2;
    unsigned short* w3t  = (unsigned short*)(ws + off); off += (size_t)N_EXP * D_DIM * F_DIM * 2;
    unsigned short* w2t  = w1t;  // aliased: w1t dead after gemm1

    hipMemsetAsync(counts, 0, 256, stream);
    hipMemsetAsync(out, 0, (size_t)out_size * sizeof(float), stream);

    int n4 = T * D_DIM / 4;
    cast_x_kernel<<<(n4 + 255) / 256, 256, 0, stream>>>(x, xb, n4);
    gate_kernel<<<T / 4, 256, 0, stream>>>(x, gw, counts, perm, wts, T);
    offsets_kernel<<<1, 64, 0, stream>>>(counts, offs);

    // w1,w3: [E][D][F] -> [E][F][D] bf16
    dim3 gt13(F_DIM / 64, D_DIM / 64, N_EXP);
    transpose_cast_kernel<<<gt13, 256, 0, stream>>>(w1, w1t, D_DIM, F_DIM);
    transpose_cast_kernel<<<gt13, 256, 0, stream>>>(w3, w3t, D_DIM, F_DIM);

    dim3 g1(T / 128, F_DIM / 64, N_EXP);
    gemm1_kernel<<<g1, 256, 0, stream>>>(xb, w1t, w3t, counts, offs, perm, hbuf, T);

    // w2: [E][F][D] -> [E][D][F] bf16 (into aliased buffer, after gemm1)
    dim3 gt2(D_DIM / 64, F_DIM / 64, N_EXP);
    transpose_cast_kernel<<<gt2, 256, 0, stream>>>(w2, w2t, F_DIM, D_DIM);

    dim3 g2(T / 128, D_DIM / 64, N_EXP);
    gemm2_kernel<<<g2, 256, 0, stream>>>(hbuf, w2t, counts, offs, perm, wts, out, T);
}

// Round 3
// 668.756 us; speedup vs baseline: 2.0173x; 1.6355x over previous
//
#include <hip/hip_runtime.h>
#include <hip/hip_bf16.h>
#include <math.h>

#define D_DIM 1024
#define F_DIM 4096
#define N_EXP 8

typedef __attribute__((ext_vector_type(4))) float f32x4;
typedef __attribute__((ext_vector_type(8))) short bf16x8;

__device__ __forceinline__ unsigned short f2bf(float f) {
    union { float f; unsigned int u; } v; v.f = f;
    unsigned int r = v.u + 0x7fffu + ((v.u >> 16) & 1u);  // RNE
    return (unsigned short)(r >> 16);
}

// async global->LDS, 16B per lane; LDS dest = lds_ptr(wave-uniform) + lane*16
#define GLDS16(g, l) __builtin_amdgcn_global_load_lds( \
    (const __attribute__((address_space(1))) void*)(g), \
    (__attribute__((address_space(3))) void*)(l), 16, 0, 0)

#define WAIT4_BAR asm volatile("s_waitcnt vmcnt(4)\ns_barrier" ::: "memory")
#define WAIT3_BAR asm volatile("s_waitcnt vmcnt(3)\ns_barrier" ::: "memory")
#define BAR       asm volatile("s_barrier" ::: "memory")

// ---------------- cast x fp32 -> bf16 ----------------
__global__ void cast_x_kernel(const float* __restrict__ x, unsigned short* __restrict__ xb, int n4) {
    int i = blockIdx.x * blockDim.x + threadIdx.x;
    if (i >= n4) return;
    float4 v = ((const float4*)x)[i];
    unsigned int lo = (unsigned int)f2bf(v.x) | ((unsigned int)f2bf(v.y) << 16);
    unsigned int hi = (unsigned int)f2bf(v.z) | ((unsigned int)f2bf(v.w) << 16);
    ((uint2*)xb)[i] = make_uint2(lo, hi);
}

// ---------------- transpose + cast: in [R][C] fp32 -> out [C][R] bf16 ----------------
__global__ __launch_bounds__(256) void transpose_cast_kernel(
    const float* __restrict__ in, unsigned short* __restrict__ out, int R, int C) {
    __shared__ float tile[64][65];
    const float* inp = in + (size_t)blockIdx.z * R * C;
    unsigned short* outp = out + (size_t)blockIdx.z * R * C;
    int r0 = blockIdx.y * 64, c0 = blockIdx.x * 64;
    int tid = threadIdx.x;
    int tr = tid >> 4, tc = (tid & 15) * 4;
#pragma unroll
    for (int i = 0; i < 4; i++) {
        float4 v = *(const float4*)(inp + (size_t)(r0 + tr + i * 16) * C + c0 + tc);
        tile[tr + i * 16][tc + 0] = v.x;
        tile[tr + i * 16][tc + 1] = v.y;
        tile[tr + i * 16][tc + 2] = v.z;
        tile[tr + i * 16][tc + 3] = v.w;
    }
    __syncthreads();
    int wc = tid >> 4, wr = (tid & 15) * 4;
#pragma unroll
    for (int i = 0; i < 4; i++) {
        int c = wc + i * 16;
        ushort4 o;
        o.x = f2bf(tile[wr + 0][c]);
        o.y = f2bf(tile[wr + 1][c]);
        o.z = f2bf(tile[wr + 2][c]);
        o.w = f2bf(tile[wr + 3][c]);
        *(ushort4*)(outp + (size_t)(c0 + c) * R + r0 + wr) = o;
    }
}

// ---------------- gating: softmax top-2 + compaction + inverse map ----------------
__global__ void gate_kernel(const float* __restrict__ x, const float* __restrict__ gw,
                            int* __restrict__ counts, int* __restrict__ perm,
                            float* __restrict__ wts, int* __restrict__ islot, int T) {
    int wid = threadIdx.x >> 6, lane = threadIdx.x & 63;
    int token = blockIdx.x * 4 + wid;
    if (token >= T) return;
    float acc[N_EXP];
#pragma unroll
    for (int e = 0; e < N_EXP; e++) acc[e] = 0.f;
    const float* xr = x + (size_t)token * D_DIM;
    for (int i = 0; i < D_DIM / 64; i++) {
        int d = lane + 64 * i;
        float v = xr[d];
#pragma unroll
        for (int e = 0; e < N_EXP; e++) acc[e] += v * gw[d * N_EXP + e];
    }
#pragma unroll
    for (int off = 32; off >= 1; off >>= 1) {
#pragma unroll
        for (int e = 0; e < N_EXP; e++) acc[e] += __shfl_xor(acc[e], off, 64);
    }
    if (lane == 0) {
        float m = acc[0];
#pragma unroll
        for (int e = 1; e < N_EXP; e++) m = fmaxf(m, acc[e]);
        float p[N_EXP];
#pragma unroll
        for (int e = 0; e < N_EXP; e++) p[e] = expf(acc[e] - m);
        int a = 0;
        for (int e = 1; e < N_EXP; e++) if (p[e] > p[a]) a = e;
        int b = (a == 0) ? 1 : 0;
        for (int e = 0; e < N_EXP; e++) if (e != a && p[e] > p[b]) b = e;
        float s = p[a] + p[b];
        int pa = atomicAdd(&counts[a], 1);
        perm[(size_t)a * T + pa] = token; wts[(size_t)a * T + pa] = p[a] / s;
        int pb = atomicAdd(&counts[b], 1);
        perm[(size_t)b * T + pb] = token; wts[(size_t)b * T + pb] = p[b] / s;
        islot[2 * token + 0] = a * T + pa;
        islot[2 * token + 1] = b * T + pb;
    }
}

__global__ void offsets_kernel(const int* __restrict__ counts, int* __restrict__ offs) {
    if (threadIdx.x == 0 && blockIdx.x == 0) {
        int s = 0;
        for (int e = 0; e < N_EXP; e++) { offs[e] = s; s += counts[e]; }
        offs[N_EXP] = s;
    }
}

// ---------------- GEMM1: H = silu(Xe@W1t) * (Xe@W3t), 128x64 tile, pipelined ----------------
__global__ __launch_bounds__(256, 4) void gemm1_kernel(
    const unsigned short* __restrict__ xb, const unsigned short* __restrict__ w1t,
    const unsigned short* __restrict__ w3t, const int* __restrict__ counts,
    const int* __restrict__ offs, const int* __restrict__ perm,
    unsigned short* __restrict__ hbuf, int T)
{
    // XCD swizzle: row tiles of one (ct,e) at blockIdx spaced by 8 -> same XCD L2
    int bid = blockIdx.x;
    int s  = bid & 7;
    int rt = (bid >> 3) & 15;
    int ce = ((bid >> 7) << 3) | s;     // 0..511
    int e  = ce & 7;
    int ct = ce >> 3;                   // 0..63
    int n_e = counts[e];
    int row0 = rt * 128;
    if (row0 >= n_e) return;
    int c0 = ct * 64;
    const unsigned short* w1e = w1t + (size_t)e * F_DIM * D_DIM;
    const unsigned short* w3e = w3t + (size_t)e * F_DIM * D_DIM;
    __shared__ unsigned short As0[4096], As1[4096];
    __shared__ unsigned short B10[2048], B11[2048];
    __shared__ unsigned short B30[2048], B31[2048];
    int tid = threadIdx.x;
    int wid = tid >> 6, lane = tid & 63;
    int wm = wid >> 1, wn = wid & 1;
    int q = lane >> 4, ln = lane & 15;

    int sr = tid >> 2, sc = tid & 3;
    int q0 = sc ^ ((sr >> 1) & 3);
    int tok0 = perm[(size_t)e * T + min(row0 + sr, n_e - 1)];
    int tok1 = perm[(size_t)e * T + min(row0 + sr + 64, n_e - 1)];
    const unsigned short* ag0 = xb + (size_t)tok0 * D_DIM + q0 * 8;
    const unsigned short* ag1 = xb + (size_t)tok1 * D_DIM + q0 * 8;
    const unsigned short* b1g = w1e + (size_t)(c0 + sr) * D_DIM + q0 * 8;
    const unsigned short* b3g = w3e + (size_t)(c0 + sr) * D_DIM + q0 * 8;
    int wo = wid * 512;

    int a_off[4], b_off[2];
#pragma unroll
    for (int i = 0; i < 4; i++) {
        int m = wm * 64 + i * 16 + ln;
        a_off[i] = m * 32 + (q ^ ((m >> 1) & 3)) * 8;
    }
#pragma unroll
    for (int j = 0; j < 2; j++) {
        int n = wn * 32 + j * 16 + ln;
        b_off[j] = n * 32 + (q ^ ((n >> 1) & 3)) * 8;
    }

    f32x4 acc1[4][2], acc3[4][2];
#pragma unroll
    for (int i = 0; i < 4; i++)
#pragma unroll
        for (int j = 0; j < 2; j++) {
            acc1[i][j] = (f32x4){0.f, 0.f, 0.f, 0.f};
            acc3[i][j] = (f32x4){0.f, 0.f, 0.f, 0.f};
        }

#define ISSUE1(AS, B1S, B3S, K) do { \
    GLDS16(ag0 + (K), &AS[wo]); \
    GLDS16(ag1 + (K), &AS[wo + 2048]); \
    GLDS16(b1g + (K), &B1S[wo]); \
    GLDS16(b3g + (K), &B3S[wo]); } while (0)

#define COMPUTE1(AS, B1S, B3S) do { \
    bf16x8 af[4]; \
    _Pragma("unroll") for (int i = 0; i < 4; i++) af[i] = *(const bf16x8*)&AS[a_off[i]]; \
    _Pragma("unroll") for (int j = 0; j < 2; j++) { \
        bf16x8 b1f = *(const bf16x8*)&B1S[b_off[j]]; \
        bf16x8 b3f = *(const bf16x8*)&B3S[b_off[j]]; \
        _Pragma("unroll") for (int i = 0; i < 4; i++) { \
            acc1[i][j] = __builtin_amdgcn_mfma_f32_16x16x32_bf16(af[i], b1f, acc1[i][j], 0, 0, 0); \
            acc3[i][j] = __builtin_amdgcn_mfma_f32_16x16x32_bf16(af[i], b3f, acc3[i][j], 0, 0, 0); \
        } \
    } } while (0)

    ISSUE1(As0, B10, B30, 0);
    for (int it = 0; it < 32; it += 2) {
        int kn1 = (it + 1) * 32;
        ISSUE1(As1, B11, B31, kn1);
        WAIT4_BAR;
        COMPUTE1(As0, B10, B30);
        BAR;
        int kn2 = (it + 2 < 32) ? (it + 2) * 32 : 0;  // final issue redundant (never read)
        ISSUE1(As0, B10, B30, kn2);
        WAIT4_BAR;
        COMPUTE1(As1, B11, B31);
        BAR;
    }

    int hb = offs[e];
#pragma unroll
    for (int i = 0; i < 4; i++) {
#pragma unroll
        for (int r = 0; r < 4; r++) {
            int grow = row0 + wm * 64 + i * 16 + q * 4 + r;
            if (grow < n_e) {
                size_t hrow = (size_t)(hb + grow) * F_DIM;
#pragma unroll
                for (int j = 0; j < 2; j++) {
                    int col = c0 + wn * 32 + j * 16 + ln;
                    float p1 = acc1[i][j][r];
                    float p3 = acc3[i][j][r];
                    float h = (p1 / (1.f + expf(-p1))) * p3;
                    hbuf[hrow + col] = f2bf(h);
                }
            }
        }
    }
}

// ---------------- GEMM2: obuf[slot] = (He @ W2t) * w, 128x64 tile, pipelined ----------------
__global__ __launch_bounds__(256, 4) void gemm2_kernel(
    const unsigned short* __restrict__ hbuf, const unsigned short* __restrict__ w2t,
    const int* __restrict__ counts, const int* __restrict__ offs,
    const float* __restrict__ wts, float* __restrict__ obuf, int T)
{
    int bid = blockIdx.x;
    int s  = bid & 7;
    int rt = (bid >> 3) & 15;
    int ce = ((bid >> 7) << 3) | s;     // 0..127
    int e  = ce & 7;
    int ct = ce >> 3;                   // 0..15
    int n_e = counts[e];
    int row0 = rt * 128;
    if (row0 >= n_e) return;
    int c0 = ct * 64;
    const unsigned short* w2e = w2t + (size_t)e * D_DIM * F_DIM;  // [D][F] bf16
    __shared__ unsigned short As0[4096], As1[4096];
    __shared__ unsigned short Bs0[2048], Bs1[2048];
    int tid = threadIdx.x;
    int wid = tid >> 6, lane = tid & 63;
    int wm = wid >> 1, wn = wid & 1;
    int q = lane >> 4, ln = lane & 15;
    int hb = offs[e];

    int sr = tid >> 2, sc = tid & 3;
    int q0 = sc ^ ((sr >> 1) & 3);
    int ar0 = hb + min(row0 + sr, n_e - 1);
    int ar1 = hb + min(row0 + sr + 64, n_e - 1);
    const unsigned short* ag0 = hbuf + (size_t)ar0 * F_DIM + q0 * 8;
    const unsigned short* ag1 = hbuf + (size_t)ar1 * F_DIM + q0 * 8;
    const unsigned short* bg  = w2e + (size_t)(c0 + sr) * F_DIM + q0 * 8;
    int wo = wid * 512;

    int a_off[4], b_off[2];
#pragma unroll
    for (int i = 0; i < 4; i++) {
        int m = wm * 64 + i * 16 + ln;
        a_off[i] = m * 32 + (q ^ ((m >> 1) & 3)) * 8;
    }
#pragma unroll
    for (int j = 0; j < 2; j++) {
        int n = wn * 32 + j * 16 + ln;
        b_off[j] = n * 32 + (q ^ ((n >> 1) & 3)) * 8;
    }

    f32x4 acc[4][2];
#pragma unroll
    for (int i = 0; i < 4; i++)
#pragma unroll
        for (int j = 0; j < 2; j++) acc[i][j] = (f32x4){0.f, 0.f, 0.f, 0.f};

#define ISSUE2(AS, BS, K) do { \
    GLDS16(ag0 + (K), &AS[wo]); \
    GLDS16(ag1 + (K), &AS[wo + 2048]); \
    GLDS16(bg + (K), &BS[wo]); } while (0)

#define COMPUTE2(AS, BS) do { \
    bf16x8 af[4]; \
    _Pragma("unroll") for (int i = 0; i < 4; i++) af[i] = *(const bf16x8*)&AS[a_off[i]]; \
    _Pragma("unroll") for (int j = 0; j < 2; j++) { \
        bf16x8 bf = *(const bf16x8*)&BS[b_off[j]]; \
        _Pragma("unroll") for (int i = 0; i < 4; i++) \
            acc[i][j] = __builtin_amdgcn_mfma_f32_16x16x32_bf16(af[i], bf, acc[i][j], 0, 0, 0); \
    } } while (0)

    ISSUE2(As0, Bs0, 0);
    for (int it = 0; it < 128; it += 2) {
        int kn1 = (it + 1) * 32;
        ISSUE2(As1, Bs1, kn1);
        WAIT3_BAR;
        COMPUTE2(As0, Bs0);
        BAR;
        int kn2 = (it + 2 < 128) ? (it + 2) * 32 : 0;
        ISSUE2(As0, Bs0, kn2);
        WAIT3_BAR;
        COMPUTE2(As1, Bs1);
        BAR;
    }

#pragma unroll
    for (int i = 0; i < 4; i++) {
#pragma unroll
        for (int r = 0; r < 4; r++) {
            int grow = row0 + wm * 64 + i * 16 + q * 4 + r;
            if (grow < n_e) {
                float w = wts[(size_t)e * T + grow];
                float* orow = obuf + (size_t)(hb + grow) * D_DIM;
#pragma unroll
                for (int j = 0; j < 2; j++) {
                    int col = c0 + wn * 32 + j * 16 + ln;
                    orow[col] = acc[i][j][r] * w;
                }
            }
        }
    }
}

// ---------------- combine: out[t] = obuf[slot0(t)] + obuf[slot1(t)] ----------------
__global__ void combine_kernel(const float* __restrict__ obuf, const int* __restrict__ islot,
                               const int* __restrict__ offs, float* __restrict__ out, int T) {
    int idx = blockIdx.x * 256 + threadIdx.x;   // one float4 each
    int n4 = T * (D_DIM / 4);
    if (idx >= n4) return;
    int t = idx / (D_DIM / 4);
    int c4 = idx - t * (D_DIM / 4);
    int v0 = islot[2 * t], v1 = islot[2 * t + 1];
    int e0 = v0 / T, e1 = v1 / T;
    int s0 = offs[e0] + (v0 - e0 * T);
    int s1 = offs[e1] + (v1 - e1 * T);
    float4 a = ((const float4*)obuf)[(size_t)s0 * (D_DIM / 4) + c4];
    float4 b = ((const float4*)obuf)[(size_t)s1 * (D_DIM / 4) + c4];
    float4 o; o.x = a.x + b.x; o.y = a.y + b.y; o.z = a.z + b.z; o.w = a.w + b.w;
    ((float4*)out)[idx] = o;
}

extern "C" void kernel_launch(void* const* d_in, const int* in_sizes, int n_in,
                              void* d_out, int out_size, void* d_ws, size_t ws_size,
                              hipStream_t stream) {
    const float* x  = (const float*)d_in[0];
    const float* gw = (const float*)d_in[1];
    const float* w1 = (const float*)d_in[2];
    const float* w2 = (const float*)d_in[3];
    const float* w3 = (const float*)d_in[4];
    float* out = (float*)d_out;
    int T = in_sizes[0] / D_DIM;   // 2048

    char* ws = (char*)d_ws;
    size_t off = 0;
    unsigned short* xb = (unsigned short*)(ws + off); off += (size_t)T * D_DIM * 2;
    int* counts = (int*)(ws + off); off += 256;
    int* offs   = (int*)(ws + off); off += 256;
    int* perm   = (int*)(ws + off); off += (size_t)N_EXP * T * 4;
    float* wts  = (float*)(ws + off); off += (size_t)N_EXP * T * 4;
    int* islot  = (int*)(ws + off); off += (size_t)2 * T * 4;
    unsigned short* hbuf = (unsigned short*)(ws + off); off += (size_t)2 * T * F_DIM * 2;
    unsigned short* w1t  = (unsigned short*)(ws + off); off += (size_t)N_EXP * D_DIM * F_DIM * 2;
    unsigned short* w3t  = (unsigned short*)(ws + off); off += (size_t)N_EXP * D_DIM * F_DIM * 2;
    unsigned short* w2t  = w1t;            // aliased: w1t dead after gemm1
    float* obuf = (float*)w3t;             // aliased: w3t dead after gemm1 (16 MB < 64 MB)

    hipMemsetAsync(counts, 0, 256, stream);

    int n4 = T * D_DIM / 4;
    cast_x_kernel<<<(n4 + 255) / 256, 256, 0, stream>>>(x, xb, n4);
    gate_kernel<<<T / 4, 256, 0, stream>>>(x, gw, counts, perm, wts, islot, T);
    offsets_kernel<<<1, 64, 0, stream>>>(counts, offs);

    dim3 gt13(F_DIM / 64, D_DIM / 64, N_EXP);
    transpose_cast_kernel<<<gt13, 256, 0, stream>>>(w1, w1t, D_DIM, F_DIM);
    transpose_cast_kernel<<<gt13, 256, 0, stream>>>(w3, w3t, D_DIM, F_DIM);

    gemm1_kernel<<<(F_DIM / 64) * N_EXP * 16, 256, 0, stream>>>(
        xb, w1t, w3t, counts, offs, perm, hbuf, T);

    dim3 gt2(D_DIM / 64, F_DIM / 64, N_EXP);
    transpose_cast_kernel<<<gt2, 256, 0, stream>>>(w2, w2t, F_DIM, D_DIM);

    gemm2_kernel<<<(D_DIM / 64) * N_EXP * 16, 256, 0, stream>>>(
        hbuf, w2t, counts, offs, wts, obuf, T);

    combine_kernel<<<(T * D_DIM / 4 + 255) / 256, 256, 0, stream>>>(obuf, islot, offs, out, T);
}